// Round 1
// baseline (19.669 us; speedup 1.0000x reference)
//
#include <hip/hip_runtime.h>
#include <math.h>

typedef _Float16 half8 __attribute__((ext_vector_type(8)));
typedef float f32x4 __attribute__((ext_vector_type(4)));

#define NN 1024
#define DD 256

// ---------------------------------------------------------------------------
// Kernel 1: row norms  ||pred[row]||^2  (f32, exact) -> ws
// 1024 blocks x 64 threads (1 wave). Lane loads float4, wave shuffle-reduce.
// ---------------------------------------------------------------------------
__global__ __launch_bounds__(64) void norms_k(const float* __restrict__ pred,
                                              float* __restrict__ norms) {
    const int row = blockIdx.x;
    const int lane = threadIdx.x;
    const float4 v = *reinterpret_cast<const float4*>(pred + (size_t)row * DD + (lane << 2));
    float s = v.x * v.x + v.y * v.y + v.z * v.z + v.w * v.w;
    #pragma unroll
    for (int off = 32; off >= 1; off >>= 1) s += __shfl_down(s, off, 64);
    if (lane == 0) norms[row] = s;
}

// Load one MFMA fragment (8 contiguous k-elements) from f32 global, cvt->f16.
__device__ __forceinline__ half8 load_frag(const float* __restrict__ p) {
    const float4 x = *reinterpret_cast<const float4*>(p);
    const float4 y = *reinterpret_cast<const float4*>(p + 4);
    half8 h;
    h[0] = (_Float16)x.x; h[1] = (_Float16)x.y; h[2] = (_Float16)x.z; h[3] = (_Float16)x.w;
    h[4] = (_Float16)y.x; h[5] = (_Float16)y.y; h[6] = (_Float16)y.z; h[7] = (_Float16)y.w;
    return h;
}

// ---------------------------------------------------------------------------
// Kernel 2: 64x64 output tile per block, 256 threads = 4 waves (2x2 of 32x32).
// C = P * P^T via mfma_f32_16x16x32_f16; fragments read directly from global
// (pred is 1 MB -> L2-resident; no LDS, no __syncthreads).
// Epilogue: dist^2 = n_i + n_j - 2*dot; dist = sqrt (0 on diagonal / d<=0);
// out = triu((dist - y_true)^2). Blocks fully below the diagonal store zeros.
// ---------------------------------------------------------------------------
__global__ __launch_bounds__(256) void pdist_k(const float* __restrict__ pred,
                                               const float* __restrict__ ytrue,
                                               const float* __restrict__ norms,
                                               float* __restrict__ out) {
    const int i0 = blockIdx.y << 6;   // row tile origin
    const int j0 = blockIdx.x << 6;   // col tile origin
    const int tid = threadIdx.x;

    if (j0 + 63 < i0) {               // entirely below diagonal -> zeros
        const float4 z = make_float4(0.f, 0.f, 0.f, 0.f);
        #pragma unroll
        for (int t = 0; t < 4; ++t) {
            const int idx = tid + (t << 8);      // 0..1023 float4 slots
            const int r = idx >> 4;              // 16 float4 per row
            const int c4 = idx & 15;
            *reinterpret_cast<float4*>(out + (size_t)(i0 + r) * NN + j0 + (c4 << 2)) = z;
        }
        return;
    }

    const int w = tid >> 6;           // wave 0..3
    const int lane = tid & 63;
    const int wr = w >> 1, wc = w & 1;
    const int rbase = i0 + (wr << 5); // wave-tile row origin (32 rows)
    const int cbase = j0 + (wc << 5); // wave-tile col origin (32 cols)
    const int l16 = lane & 15;
    const int kq = (lane >> 4) << 3;  // this lane's k-offset within a 32-chunk

    f32x4 acc[2][2] = {};

    #pragma unroll
    for (int ks = 0; ks < 8; ++ks) {  // K = 256 = 8 * 32
        const int k = (ks << 5) + kq;
        half8 a[2], b[2];
        #pragma unroll
        for (int m = 0; m < 2; ++m)
            a[m] = load_frag(pred + (size_t)(rbase + (m << 4) + l16) * DD + k);
        #pragma unroll
        for (int n = 0; n < 2; ++n)
            b[n] = load_frag(pred + (size_t)(cbase + (n << 4) + l16) * DD + k);
        #pragma unroll
        for (int m = 0; m < 2; ++m)
            #pragma unroll
            for (int n = 0; n < 2; ++n)
                acc[m][n] = __builtin_amdgcn_mfma_f32_16x16x32_f16(a[m], b[n], acc[m][n], 0, 0, 0);
    }

    // Epilogue. C/D layout: col = lane&15, row = (lane>>4)*4 + reg  [m89].
    const int rq = (lane >> 4) << 2;
    #pragma unroll
    for (int m = 0; m < 2; ++m) {
        // 4 consecutive rows for this lane in this m-tile -> float4 norm load
        const int row0 = rbase + (m << 4) + rq;
        const float4 nr4 = *reinterpret_cast<const float4*>(norms + row0);
        const float nr[4] = {nr4.x, nr4.y, nr4.z, nr4.w};
        #pragma unroll
        for (int n = 0; n < 2; ++n) {
            const int col = cbase + (n << 4) + l16;
            const float ncol = norms[col];
            #pragma unroll
            for (int v = 0; v < 4; ++v) {
                const int row = row0 + v;
                const float d2 = nr[v] + ncol - 2.0f * acc[m][n][v];
                const float val = (row == col || d2 <= 0.f) ? 0.f : sqrtf(d2);
                const float t = ytrue[(size_t)row * NN + col];
                const float diff = val - t;
                out[(size_t)row * NN + col] = (col >= row) ? diff * diff : 0.f;
            }
        }
    }
}

extern "C" void kernel_launch(void* const* d_in, const int* in_sizes, int n_in,
                              void* d_out, int out_size, void* d_ws, size_t ws_size,
                              hipStream_t stream) {
    const float* y_true = (const float*)d_in[0];   // (1024, 1024)
    const float* y_pred = (const float*)d_in[1];   // (1024, 256)
    float* out = (float*)d_out;
    float* norms = (float*)d_ws;                   // 4 KB scratch

    hipLaunchKernelGGL(norms_k, dim3(NN), dim3(64), 0, stream, y_pred, norms);
    hipLaunchKernelGGL(pdist_k, dim3(16, 16), dim3(256), 0, stream,
                       y_pred, y_true, norms, out);
}

// Round 2
// 15.485 us; speedup vs baseline: 1.2703x; 1.2703x over previous
//
#include <hip/hip_runtime.h>
#include <math.h>

typedef _Float16 half8 __attribute__((ext_vector_type(8)));
typedef _Float16 half4 __attribute__((ext_vector_type(4)));
typedef float f32x4 __attribute__((ext_vector_type(4)));

#define NN 1024
#define DD 256

// ---------------------------------------------------------------------------
// Kernel 1: prep — read pred (f32, coalesced), compute row norms (f32 exact),
// and write a f16 copy pre-swizzled into MFMA-fragment order:
//   chunk c = k>>3 (32 chunks), addr16B = (c*1024 + row), 8 f16 per slot.
// So a fragment load in the GEMM is ONE dwordx4 and 16 consecutive lanes
// (consecutive rows) read 256B contiguous.
// Grid: 256 blocks x 256 thr = 4 waves/block, one row per wave.
// ---------------------------------------------------------------------------
__global__ __launch_bounds__(256) void prep_k(const float* __restrict__ pred,
                                              _Float16* __restrict__ p16,
                                              float* __restrict__ norms) {
    const int w = threadIdx.x >> 6;
    const int lane = threadIdx.x & 63;
    const int row = (blockIdx.x << 2) + w;

    const float4 v = *reinterpret_cast<const float4*>(pred + (size_t)row * DD + (lane << 2));
    float s = v.x * v.x + v.y * v.y + v.z * v.z + v.w * v.w;
    #pragma unroll
    for (int off = 32; off >= 1; off >>= 1) s += __shfl_xor(s, off, 64);
    if (lane == 0) norms[row] = s;

    half4 h;
    h[0] = (_Float16)v.x; h[1] = (_Float16)v.y;
    h[2] = (_Float16)v.z; h[3] = (_Float16)v.w;
    const int c = lane >> 1;            // k-chunk = (4*lane)>>3
    const int j = (lane & 1) << 2;      // low/high half of the 8-f16 slot
    *reinterpret_cast<half4*>(p16 + ((((size_t)c << 10) + row) << 3) + j) = h;
}

// ---------------------------------------------------------------------------
// Kernel 2: 64x64 output tile per block, 4 waves (2x2 of 32x32), K=256.
// Fragments load directly from the swizzled f16 copy (L2-resident, 16B/lane).
// dist^2 = n_i + n_j - 2*dot;  out = triu((sqrt(dist^2) - y_true)^2),
// diagonal/d2<=0 forced to 0. Blocks fully below the diagonal store zeros.
// ---------------------------------------------------------------------------
__global__ __launch_bounds__(256) void pdist_k(const _Float16* __restrict__ p16,
                                               const float* __restrict__ ytrue,
                                               const float* __restrict__ norms,
                                               float* __restrict__ out) {
    const int i0 = blockIdx.y << 6;   // row tile origin
    const int j0 = blockIdx.x << 6;   // col tile origin
    const int tid = threadIdx.x;

    if (j0 + 63 < i0) {               // entirely below diagonal -> zeros
        const float4 z = make_float4(0.f, 0.f, 0.f, 0.f);
        #pragma unroll
        for (int t = 0; t < 4; ++t) {
            const int idx = tid + (t << 8);
            const int r = idx >> 4;
            const int c4 = idx & 15;
            *reinterpret_cast<float4*>(out + (size_t)(i0 + r) * NN + j0 + (c4 << 2)) = z;
        }
        return;
    }

    const int w = tid >> 6;           // wave 0..3
    const int lane = tid & 63;
    const int wr = w >> 1, wc = w & 1;
    const int rbase = i0 + (wr << 5);
    const int cbase = j0 + (wc << 5);
    const int l16 = lane & 15;
    const int lq = lane >> 4;         // 0..3 -> k-quarter within a 32-chunk

    f32x4 acc[2][2] = {};

    #pragma unroll
    for (int ks = 0; ks < 8; ++ks) {  // K = 256 = 8 * 32
        const int c = (ks << 2) + lq; // chunk index
        const size_t cb = ((size_t)c << 13);   // c * 1024 rows * 8 f16
        half8 a[2], b[2];
        #pragma unroll
        for (int m = 0; m < 2; ++m)
            a[m] = *reinterpret_cast<const half8*>(p16 + cb + (((size_t)(rbase + (m << 4) + l16)) << 3));
        #pragma unroll
        for (int n = 0; n < 2; ++n)
            b[n] = *reinterpret_cast<const half8*>(p16 + cb + (((size_t)(cbase + (n << 4) + l16)) << 3));
        #pragma unroll
        for (int m = 0; m < 2; ++m)
            #pragma unroll
            for (int n = 0; n < 2; ++n)
                acc[m][n] = __builtin_amdgcn_mfma_f32_16x16x32_f16(a[m], b[n], acc[m][n], 0, 0, 0);
    }

    // Epilogue. C/D layout: col = lane&15, row = (lane>>4)*4 + reg  [m89].
    const int rq = lq << 2;
    #pragma unroll
    for (int m = 0; m < 2; ++m) {
        const int row0 = rbase + (m << 4) + rq;
        const float4 nr4 = *reinterpret_cast<const float4*>(norms + row0);
        const float nr[4] = {nr4.x, nr4.y, nr4.z, nr4.w};
        #pragma unroll
        for (int n = 0; n < 2; ++n) {
            const int col = cbase + (n << 4) + l16;
            const float ncol = norms[col];
            #pragma unroll
            for (int v = 0; v < 4; ++v) {
                const int row = row0 + v;
                const float d2 = nr[v] + ncol - 2.0f * acc[m][n][v];
                const float val = (row == col || d2 <= 0.f) ? 0.f : sqrtf(d2);
                const float t = ytrue[(size_t)row * NN + col];
                const float diff = val - t;
                out[(size_t)row * NN + col] = (col >= row) ? diff * diff : 0.f;
            }
        }
    }
}

extern "C" void kernel_launch(void* const* d_in, const int* in_sizes, int n_in,
                              void* d_out, int out_size, void* d_ws, size_t ws_size,
                              hipStream_t stream) {
    const float* y_true = (const float*)d_in[0];   // (1024, 1024)
    const float* y_pred = (const float*)d_in[1];   // (1024, 256)
    float* out = (float*)d_out;

    _Float16* p16 = (_Float16*)d_ws;                       // 512 KB swizzled f16 pred
    float* norms = (float*)((char*)d_ws + (size_t)NN * DD * 2);  // 4 KB norms

    hipLaunchKernelGGL(prep_k, dim3(NN / 4), dim3(256), 0, stream, y_pred, p16, norms);
    hipLaunchKernelGGL(pdist_k, dim3(16, 16), dim3(256), 0, stream,
                       p16, y_true, norms, out);
}

// Round 3
// 15.435 us; speedup vs baseline: 1.2743x; 1.0032x over previous
//
#include <hip/hip_runtime.h>
#include <math.h>

typedef _Float16 half8 __attribute__((ext_vector_type(8)));
typedef _Float16 half4 __attribute__((ext_vector_type(4)));
typedef float f32x4 __attribute__((ext_vector_type(4)));

#define NN 1024
#define DD 256

// ---------------------------------------------------------------------------
// Single fused kernel. Grid 16x16, 256 threads (4 waves, 2x2 of 32x32 tiles).
// Per block: 64x64 output tile.
//  - lower blocks (bj<bi): store zeros, exit.
//  - stage1: rows i0..i0+63 (A) and j0..j0+63 (B) of pred -> f16 in LDS,
//    layout lds16[row 0..127][slot 0..31] of 16B, slot = chunk ^ (row&7)
//    (XOR swizzle: conflict-free for both the 8B writes and b128 reads).
//  - k-loop: Gram via mfma(colFrag, rowFrag) -> lane holds 4 consecutive COLS
//    per acc (transposed orientation). Row/col norms accumulated by MFMA with
//    a ones-fragment: nr = mfma(ones, rowFrag^2), nc = mfma(colFrag^2, ones).
//  - epilogue: d2 = nr + nc - 2*dot; dist = sqrt (0 on diag / d2<=0);
//    out = triu((dist - y_true)^2), float4 loads/stores (y_true prefetched
//    into registers at kernel top to hide HBM latency).
// ---------------------------------------------------------------------------
__global__ __launch_bounds__(256) void fused_k(const float* __restrict__ pred,
                                               const float* __restrict__ ytrue,
                                               float* __restrict__ out) {
    const int bi = blockIdx.y, bj = blockIdx.x;
    const int i0 = bi << 6, j0 = bj << 6;
    const int tid = threadIdx.x;

    if (bj < bi) {                    // entirely below diagonal -> zeros
        const float4 z = make_float4(0.f, 0.f, 0.f, 0.f);
        #pragma unroll
        for (int t = 0; t < 4; ++t) {
            const int idx = tid + (t << 8);
            const int r = idx >> 4, c4 = idx & 15;
            *reinterpret_cast<float4*>(out + (size_t)(i0 + r) * NN + j0 + (c4 << 2)) = z;
        }
        return;
    }

    extern __shared__ char smem[];    // 64 KB
    _Float16* lds = reinterpret_cast<_Float16*>(smem);

    const int w = tid >> 6;           // wave 0..3
    const int lane = tid & 63;
    const int l16 = lane & 15;
    const int lq = lane >> 4;
    const int rq = lq << 2;
    const int wr = w >> 1, wc = w & 1;

    // ---- y_true prefetch (float4/lane; consumed only in epilogue) ----
    float4 t4[2][2];
    #pragma unroll
    for (int m = 0; m < 2; ++m) {
        const int row = i0 + (wr << 5) + (m << 4) + l16;
        #pragma unroll
        for (int n = 0; n < 2; ++n) {
            const int col = j0 + (wc << 5) + (n << 4) + rq;
            t4[m][n] = *reinterpret_cast<const float4*>(ytrue + (size_t)row * NN + col);
        }
    }

    // ---- stage1: coalesced f32 row loads -> f16 swizzled LDS ----
    const int c = lane >> 1;              // chunk 0..31 (= (lane*4)>>3)
    const int jhalf = (lane & 1) << 2;    // which 8B half of the 16B slot
    #pragma unroll
    for (int it = 0; it < 32; ++it) {
        const int lr = (it << 2) + w;     // lds row 0..127
        const int grow = (lr < 64) ? (i0 + lr) : (j0 + lr - 64);
        const float4 v = *reinterpret_cast<const float4*>(pred + (size_t)grow * DD + (lane << 2));
        half4 h;
        h[0] = (_Float16)v.x; h[1] = (_Float16)v.y;
        h[2] = (_Float16)v.z; h[3] = (_Float16)v.w;
        const int slot = c ^ (lr & 7);
        *reinterpret_cast<half4*>(lds + (((lr << 5) + slot) << 3) + jhalf) = h;
    }
    __syncthreads();

    // ---- k-loop: K = 256 = 8 chunks-of-32 ----
    f32x4 acc[2][2] = {};
    f32x4 nr[2] = {};                 // row norms  (ones x rowFrag^2)
    f32x4 nc[2] = {};                 // col norms  (colFrag^2 x ones)
    half8 ones;
    #pragma unroll
    for (int q = 0; q < 8; ++q) ones[q] = (_Float16)1.0f;

    #pragma unroll
    for (int ks = 0; ks < 8; ++ks) {
        const int cc = (ks << 2) + lq;
        half8 fa[2], fb[2];
        #pragma unroll
        for (int m = 0; m < 2; ++m) {
            const int lr = (wr << 5) + (m << 4) + l16;
            fa[m] = *reinterpret_cast<const half8*>(lds + (((lr << 5) + (cc ^ (lr & 7))) << 3));
        }
        #pragma unroll
        for (int n = 0; n < 2; ++n) {
            const int lr = 64 + (wc << 5) + (n << 4) + l16;
            fb[n] = *reinterpret_cast<const half8*>(lds + (((lr << 5) + (cc ^ (lr & 7))) << 3));
        }
        #pragma unroll
        for (int m = 0; m < 2; ++m)
            #pragma unroll
            for (int n = 0; n < 2; ++n)
                acc[m][n] = __builtin_amdgcn_mfma_f32_16x16x32_f16(fb[n], fa[m], acc[m][n], 0, 0, 0);
        #pragma unroll
        for (int m = 0; m < 2; ++m)
            nr[m] = __builtin_amdgcn_mfma_f32_16x16x32_f16(ones, fa[m] * fa[m], nr[m], 0, 0, 0);
        #pragma unroll
        for (int n = 0; n < 2; ++n)
            nc[n] = __builtin_amdgcn_mfma_f32_16x16x32_f16(fb[n] * fb[n], ones, nc[n], 0, 0, 0);
    }

    // ---- epilogue: acc[m][n][v] = Gram[row = i0+wr*32+m*16+l16]
    //                                   [col = j0+wc*32+n*16+rq+v]      ----
    #pragma unroll
    for (int m = 0; m < 2; ++m) {
        const int row = i0 + (wr << 5) + (m << 4) + l16;
        const float nrow = nr[m][0];
        #pragma unroll
        for (int n = 0; n < 2; ++n) {
            const int col0 = j0 + (wc << 5) + (n << 4) + rq;
            float4 o;
            float* po = &o.x;
            const float* pt = &t4[m][n].x;
            #pragma unroll
            for (int v = 0; v < 4; ++v) {
                const int col = col0 + v;
                const float d2 = nrow + nc[n][v] - 2.0f * acc[m][n][v];
                const float val = (row == col || d2 <= 0.f) ? 0.f : sqrtf(d2);
                const float diff = val - pt[v];
                po[v] = (col >= row) ? diff * diff : 0.f;
            }
            *reinterpret_cast<float4*>(out + (size_t)row * NN + col0) = o;
        }
    }
}

extern "C" void kernel_launch(void* const* d_in, const int* in_sizes, int n_in,
                              void* d_out, int out_size, void* d_ws, size_t ws_size,
                              hipStream_t stream) {
    const float* y_true = (const float*)d_in[0];   // (1024, 1024)
    const float* y_pred = (const float*)d_in[1];   // (1024, 256)
    float* out = (float*)d_out;

    hipLaunchKernelGGL(fused_k, dim3(16, 16), dim3(256), 65536, stream,
                       y_pred, y_true, out);
}

// Round 4
// 14.600 us; speedup vs baseline: 1.3473x; 1.0572x over previous
//
#include <hip/hip_runtime.h>
#include <math.h>

typedef _Float16 half8 __attribute__((ext_vector_type(8)));
typedef _Float16 half4 __attribute__((ext_vector_type(4)));
typedef float f32x4 __attribute__((ext_vector_type(4)));

#define NN 1024
#define DD 256

// ---------------------------------------------------------------------------
// Kernel 1: prep — f32 pred -> f16 copy in ws, pre-swizzled to fragment order:
//   p16 viewed as [chunk c = k>>3][row][8 f16]; a GEMM fragment load is ONE
//   dwordx4 and 16 consecutive lanes read 256B contiguous.
// (No norm computation here — norms come free via MFMA in kernel 2.)
// ---------------------------------------------------------------------------
__global__ __launch_bounds__(256) void prep_k(const float* __restrict__ pred,
                                              _Float16* __restrict__ p16) {
    const int w = threadIdx.x >> 6;
    const int lane = threadIdx.x & 63;
    const int row = (blockIdx.x << 2) + w;

    const float4 v = *reinterpret_cast<const float4*>(pred + (size_t)row * DD + (lane << 2));
    half4 h;
    h[0] = (_Float16)v.x; h[1] = (_Float16)v.y;
    h[2] = (_Float16)v.z; h[3] = (_Float16)v.w;
    const int c = lane >> 1;            // k-chunk = (4*lane)>>3
    const int j = (lane & 1) << 2;      // low/high half of the 8-f16 slot
    *reinterpret_cast<half4*>(p16 + ((((size_t)c << 10) + row) << 3) + j) = h;
}

// ---------------------------------------------------------------------------
// Kernel 2: 32x32 output tile per block, grid 32x32 = 1024 blocks (528 real),
// 256 threads = 4 waves, each wave owns a 16x16 quadrant with full K=256.
// No LDS, no syncthreads: fragments straight from L2-resident swizzled ws.
// Norms via MFMA with a ones fragment (proven R3). Transposed acc orientation
// (acc = mfma(fb, fa)) so each lane holds 4 consecutive COLUMNS -> float4
// y_true loads and out stores.
// ---------------------------------------------------------------------------
__global__ __launch_bounds__(256, 4) void pdist_k(const _Float16* __restrict__ p16,
                                                  const float* __restrict__ ytrue,
                                                  float* __restrict__ out) {
    const int bi = blockIdx.y, bj = blockIdx.x;
    const int i0 = bi << 5, j0 = bj << 5;
    const int tid = threadIdx.x;

    if (bj < bi) {                    // entirely below diagonal -> zeros
        const int r = tid >> 3, c4 = tid & 7;   // 256 float4 slots = 32x32
        *reinterpret_cast<float4*>(out + (size_t)(i0 + r) * NN + j0 + (c4 << 2)) =
            make_float4(0.f, 0.f, 0.f, 0.f);
        return;
    }

    const int w = tid >> 6;           // wave 0..3 -> 2x2 quadrants of 16x16
    const int lane = tid & 63;
    const int l16 = lane & 15;
    const int lq = lane >> 4;
    const int rq = lq << 2;
    const int wr = w >> 1, wc = w & 1;

    const int row = i0 + (wr << 4) + l16;    // this lane's output row
    const int col0 = j0 + (wc << 4) + rq;    // first of its 4 output cols
    const int arow = row;                    // A-fragment source row
    const int brow = j0 + (wc << 4) + l16;   // B-fragment source row (a col)

    // y_true prefetch — HBM latency hides under the k-loop
    const float4 t4 = *reinterpret_cast<const float4*>(ytrue + (size_t)row * NN + col0);

    f32x4 acc = {}, nr = {}, nc = {};
    half8 ones;
    #pragma unroll
    for (int q = 0; q < 8; ++q) ones[q] = (_Float16)1.0f;

    #pragma unroll
    for (int ks = 0; ks < 8; ++ks) {  // K = 256 = 8 chunks of 32
        const int c = (ks << 2) + lq;
        const size_t cb = (size_t)c << 13;    // c * 1024 rows * 8 f16
        const half8 fa = *reinterpret_cast<const half8*>(p16 + cb + ((size_t)arow << 3));
        const half8 fb = *reinterpret_cast<const half8*>(p16 + cb + ((size_t)brow << 3));
        acc = __builtin_amdgcn_mfma_f32_16x16x32_f16(fb, fa, acc, 0, 0, 0);
        nr  = __builtin_amdgcn_mfma_f32_16x16x32_f16(ones, fa * fa, nr, 0, 0, 0);
        nc  = __builtin_amdgcn_mfma_f32_16x16x32_f16(fb * fb, ones, nc, 0, 0, 0);
    }

    // acc[v] = Gram[row][col0+v]; nr[*] = ||row||^2; nc[v] = ||col0+v||^2
    const float nrow = nr[0];
    float4 o;
    float* po = &o.x;
    const float* pt = &t4.x;
    #pragma unroll
    for (int v = 0; v < 4; ++v) {
        const int col = col0 + v;
        const float d2 = nrow + nc[v] - 2.0f * acc[v];
        const float val = (row == col || d2 <= 0.f) ? 0.f : sqrtf(d2);
        const float diff = val - pt[v];
        po[v] = (col >= row) ? diff * diff : 0.f;
    }
    *reinterpret_cast<float4*>(out + (size_t)row * NN + col0) = o;
}

extern "C" void kernel_launch(void* const* d_in, const int* in_sizes, int n_in,
                              void* d_out, int out_size, void* d_ws, size_t ws_size,
                              hipStream_t stream) {
    const float* y_true = (const float*)d_in[0];   // (1024, 1024)
    const float* y_pred = (const float*)d_in[1];   // (1024, 256)
    float* out = (float*)d_out;
    _Float16* p16 = (_Float16*)d_ws;               // 512 KB swizzled f16 pred

    hipLaunchKernelGGL(prep_k, dim3(NN / 4), dim3(256), 0, stream, y_pred, p16);
    hipLaunchKernelGGL(pdist_k, dim3(32, 32), dim3(256), 0, stream,
                       p16, y_true, out);
}